// Round 5
// baseline (177.532 us; speedup 1.0000x reference)
//
#include <hip/hip_runtime.h>
#include <math.h>
#include <string.h>

// LinearAttention3D, B=2, C=64, N = 128*128*16 = 262144, HEADS=2, DIM_HEAD=1.
// softmax over dim_head (size 1) == 1.0, SCALE == 1.0 -> q/query/W_q are dead.
// out[b,o,n] = W_out[o,:] . ctx[b,:] + b_out[o] (constant over n), where
// ctx[b,h] = (sum_n e^{k_h(n)} v_h(n)) / (sum_n e^{k_h(n)}).
// |k| <~ 5 so unstabilized fp32 exp-sums are safe -> combine is a plain add.
//
// Single persistent kernel, manual grid barrier:
//   phase A: reduce 128 float4-cols/block -> partial[bid] (1024 partials)
//   barrier: threadfence + atomicAdd + acquire-spin (counter memset per launch)
//   phase B: every block re-sums all partials (fixed order, agent-scope atomic
//            loads -> XCD-coherent), computes its row value, fills 128KB slice.
// Co-residency guaranteed: __launch_bounds__(256,4) => 4 blocks/CU * 256 CUs
// = 1024 = GRID, so the barrier cannot deadlock.

#define C_IN 64
#define COLS 65536                 // float4 columns per batch
#define BLK  256
#define GRID 1024
#define BPB  512                   // blocks per batch
#define CPB  128                   // float4-cols per block (2 passes of 64)
#define F4_PER_BLK 8192            // out float4 per block (8388608 / 1024)

__global__ __launch_bounds__(BLK, 4) void fused_linattn(
    const float* __restrict__ x, const float* __restrict__ Wqkv,
    const float* __restrict__ Wout, const float* __restrict__ bout,
    float4* __restrict__ out, float4* __restrict__ partials,
    unsigned int* __restrict__ cnt)
{
    __shared__ float  s_w[4][C_IN];   // W_qkv rows 2..5: k_h0, k_h1, v_h0, v_h1
    __shared__ float4 s_red[4];
    __shared__ float  s_ctx[2][2];
    __shared__ float  s_vals[128];

    const int tid  = threadIdx.x;
    const int wave = tid >> 6;
    const int lane = tid & 63;
    const int bid  = blockIdx.x;
    const int b    = bid >> 9;            // 0..1
    const int blk  = bid & (BPB - 1);     // 0..511

    // ---------------- Phase A: fused k/v projection + exp-sum reduce ---------
    s_w[tid >> 6][tid & 63] = Wqkv[(2 + (tid >> 6)) * C_IN + (tid & 63)];
    __syncthreads();

    const int chunk = lane >> 4;          // 0..3 -> channels [16*chunk, +16)
    const int c0    = chunk << 4;

    float s0 = 0.f, sv0 = 0.f, s1 = 0.f, sv1 = 0.f;

    for (int p = 0; p < 2; ++p) {
        const int col = blk * CPB + p * 64 + (wave << 4) + (lane & 15);
        const float4* xp = reinterpret_cast<const float4*>(x)
                           + (size_t)b * C_IN * COLS + (size_t)c0 * COLS + col;

        float4 kh0 = make_float4(0.f, 0.f, 0.f, 0.f);
        float4 kh1 = kh0, vh0 = kh0, vh1 = kh0;

        #pragma unroll
        for (int i = 0; i < 16; ++i) {
            float4 xv = xp[(size_t)i * COLS];   // 4x 256B segments per wave-load
            float wk0 = s_w[0][c0 + i], wk1 = s_w[1][c0 + i];
            float wv0 = s_w[2][c0 + i], wv1 = s_w[3][c0 + i];
            kh0.x = fmaf(xv.x, wk0, kh0.x); kh0.y = fmaf(xv.y, wk0, kh0.y);
            kh0.z = fmaf(xv.z, wk0, kh0.z); kh0.w = fmaf(xv.w, wk0, kh0.w);
            kh1.x = fmaf(xv.x, wk1, kh1.x); kh1.y = fmaf(xv.y, wk1, kh1.y);
            kh1.z = fmaf(xv.z, wk1, kh1.z); kh1.w = fmaf(xv.w, wk1, kh1.w);
            vh0.x = fmaf(xv.x, wv0, vh0.x); vh0.y = fmaf(xv.y, wv0, vh0.y);
            vh0.z = fmaf(xv.z, wv0, vh0.z); vh0.w = fmaf(xv.w, wv0, vh0.w);
            vh1.x = fmaf(xv.x, wv1, vh1.x); vh1.y = fmaf(xv.y, wv1, vh1.y);
            vh1.z = fmaf(xv.z, wv1, vh1.z); vh1.w = fmaf(xv.w, wv1, vh1.w);
        }

        // Complete the dots across the 4 channel-chunks (lanes 16 apart share a
        // column); afterwards all 4 replicas hold identical full dots.
        #pragma unroll
        for (int off = 16; off <= 32; off <<= 1) {
            kh0.x += __shfl_xor(kh0.x, off); kh0.y += __shfl_xor(kh0.y, off);
            kh0.z += __shfl_xor(kh0.z, off); kh0.w += __shfl_xor(kh0.w, off);
            kh1.x += __shfl_xor(kh1.x, off); kh1.y += __shfl_xor(kh1.y, off);
            kh1.z += __shfl_xor(kh1.z, off); kh1.w += __shfl_xor(kh1.w, off);
            vh0.x += __shfl_xor(vh0.x, off); vh0.y += __shfl_xor(vh0.y, off);
            vh0.z += __shfl_xor(vh0.z, off); vh0.w += __shfl_xor(vh0.w, off);
            vh1.x += __shfl_xor(vh1.x, off); vh1.y += __shfl_xor(vh1.y, off);
            vh1.z += __shfl_xor(vh1.z, off); vh1.w += __shfl_xor(vh1.w, off);
        }

        float e;
        e = __expf(kh0.x); s0 += e; sv0 = fmaf(e, vh0.x, sv0);
        e = __expf(kh0.y); s0 += e; sv0 = fmaf(e, vh0.y, sv0);
        e = __expf(kh0.z); s0 += e; sv0 = fmaf(e, vh0.z, sv0);
        e = __expf(kh0.w); s0 += e; sv0 = fmaf(e, vh0.w, sv0);
        e = __expf(kh1.x); s1 += e; sv1 = fmaf(e, vh1.x, sv1);
        e = __expf(kh1.y); s1 += e; sv1 = fmaf(e, vh1.y, sv1);
        e = __expf(kh1.z); s1 += e; sv1 = fmaf(e, vh1.z, sv1);
        e = __expf(kh1.w); s1 += e; sv1 = fmaf(e, vh1.w, sv1);
    }

    // Sum the 16 distinct columns within each 16-lane group (replicas across
    // groups identical; off>=16 would double-count).
    #pragma unroll
    for (int off = 1; off <= 8; off <<= 1) {
        s0  += __shfl_xor(s0,  off);
        sv0 += __shfl_xor(sv0, off);
        s1  += __shfl_xor(s1,  off);
        sv1 += __shfl_xor(sv1, off);
    }
    if (lane == 0) s_red[wave] = make_float4(s0, sv0, s1, sv1);
    __syncthreads();
    if (tid == 0) {
        float4 r0 = s_red[0], r1 = s_red[1], r2 = s_red[2], r3 = s_red[3];
        partials[bid] = make_float4(r0.x + r1.x + r2.x + r3.x,
                                    r0.y + r1.y + r2.y + r3.y,
                                    r0.z + r1.z + r2.z + r3.z,
                                    r0.w + r1.w + r2.w + r3.w);
    }

    // ---------------- manual grid barrier ----------------
    if (tid == 0) {
        __threadfence();                        // release partials (agent scope)
        atomicAdd(cnt, 1u);
        while (__hip_atomic_load(cnt, __ATOMIC_ACQUIRE,
                                 __HIP_MEMORY_SCOPE_AGENT) < GRID)
            __builtin_amdgcn_s_sleep(8);
    }
    __syncthreads();

    // ---------------- Phase B: combine (fixed order) + fill ------------------
    // wave w owns (bb,h) = (w>>1, w&1); partials entry i = {s0,sv0,s1,sv1};
    // read (s,sv) pairs as agent-scope atomic 8B loads (XCD-coherent).
    {
        const int bb = wave >> 1, h = wave & 1;
        const unsigned long long* pp =
            reinterpret_cast<const unsigned long long*>(partials);
        float s = 0.f, sv = 0.f;
        #pragma unroll
        for (int i = 0; i < BPB / 64; ++i) {    // 8 iterations
            unsigned long long raw = __hip_atomic_load(
                pp + ((size_t)(bb * BPB + i * 64 + lane) * 2 + h),
                __ATOMIC_RELAXED, __HIP_MEMORY_SCOPE_AGENT);
            float2 t;
            memcpy(&t, &raw, 8);
            s += t.x; sv += t.y;
        }
        #pragma unroll
        for (int off = 1; off <= 32; off <<= 1) {
            s  += __shfl_xor(s,  off);
            sv += __shfl_xor(sv, off);
        }
        if (lane == 0) s_ctx[bb][h] = sv / s;
    }
    __syncthreads();
    if (tid < 128) {
        const int bb = tid >> 6, o = tid & 63;
        s_vals[tid] = fmaf(Wout[o * 2 + 0], s_ctx[bb][0],
                      fmaf(Wout[o * 2 + 1], s_ctx[bb][1], bout[o]));
    }
    __syncthreads();

    // Fill this block's contiguous 128KB slice (8 blocks per output row).
    const int row = bid >> 3;                   // b*64 + o
    const float v = s_vals[row];
    const float4 f4 = make_float4(v, v, v, v);
    const size_t base = (size_t)bid * F4_PER_BLK;
    #pragma unroll 8
    for (int k = 0; k < F4_PER_BLK / BLK; ++k)
        out[base + ((size_t)k << 8) + tid] = f4;
}

extern "C" void kernel_launch(void* const* d_in, const int* in_sizes, int n_in,
                              void* d_out, int out_size, void* d_ws, size_t ws_size,
                              hipStream_t stream) {
    const float* x    = (const float*)d_in[0];
    // d_in[1] = query : dead (softmax over size-1 dim == 1)
    const float* Wqkv = (const float*)d_in[2];
    // d_in[3] = W_q   : dead
    const float* Wout = (const float*)d_in[4];
    const float* bout = (const float*)d_in[5];
    float4* out = (float4*)d_out;

    float4* partials = (float4*)d_ws;                          // 1024*16B = 16KB
    unsigned int* cnt = (unsigned int*)((char*)d_ws + 32768);  // barrier counter

    hipMemsetAsync(cnt, 0, sizeof(unsigned int), stream);      // graph-capturable
    fused_linattn<<<GRID, BLK, 0, stream>>>(x, Wqkv, Wout, bout, out,
                                            partials, cnt);
}

// Round 6
// 161.441 us; speedup vs baseline: 1.0997x; 1.0997x over previous
//
#include <hip/hip_runtime.h>
#include <math.h>
#include <string.h>

// LinearAttention3D, B=2, C=64, N = 128*128*16 = 262144, HEADS=2, DIM_HEAD=1.
// softmax over dim_head (size 1) == 1.0, SCALE == 1.0 -> q/query/W_q are dead.
// out[b,o,n] = W_out[o,:] . ctx[b,:] + b_out[o] (constant over n), where
// ctx[b,h] = (sum_n e^{k_h(n)} v_h(n)) / (sum_n e^{k_h(n)}).
// |k| <~ 5 so unstabilized fp32 exp-sums are safe -> combine is a plain add.
//
// Single persistent kernel with manual grid barrier. R5 lesson: the barrier
// must poll RARELY and with RELAXED loads — s_sleep(8)+ACQUIRE-per-poll
// saturated the counter's L2 slice / fabric and throttled phase A to 1 TB/s.
// Here: first check before any sleep, s_sleep(127) (~3.4us) between RELAXED
// polls, single ACQUIRE load on exit. Phase-B partial reads are agent-scope
// RELAXED 8B atomic loads (bypass L1, coherent across XCDs) — proven in R5.
// Co-residency: __launch_bounds__(256,4) (4 waves/EU -> 4 blocks/CU) and
// GRID = 4 * 256 CUs = 1024, so the barrier cannot deadlock. VGPR=64 (R5).

#define C_IN 64
#define COLS 65536                 // float4 columns per batch
#define BLK  256
#define GRID 1024
#define BPB  512                   // blocks per batch
#define CPB  128                   // float4-cols per block (2 passes of 64)
#define F4_PER_BLK 8192            // out float4 per block (8388608 / 1024)

__global__ __launch_bounds__(BLK, 4) void fused_linattn(
    const float* __restrict__ x, const float* __restrict__ Wqkv,
    const float* __restrict__ Wout, const float* __restrict__ bout,
    float4* __restrict__ out, float4* __restrict__ partials,
    unsigned int* __restrict__ cnt)
{
    __shared__ float  s_w[4][C_IN];   // W_qkv rows 2..5: k_h0, k_h1, v_h0, v_h1
    __shared__ float4 s_red[4];
    __shared__ float  s_ctx[2][2];
    __shared__ float  s_vals[128];

    const int tid  = threadIdx.x;
    const int wave = tid >> 6;
    const int lane = tid & 63;
    const int bid  = blockIdx.x;
    const int b    = bid >> 9;            // 0..1
    const int blk  = bid & (BPB - 1);     // 0..511

    // ---------------- Phase A: fused k/v projection + exp-sum reduce ---------
    s_w[tid >> 6][tid & 63] = Wqkv[(2 + (tid >> 6)) * C_IN + (tid & 63)];
    __syncthreads();

    const int chunk = lane >> 4;          // 0..3 -> channels [16*chunk, +16)
    const int c0    = chunk << 4;

    float s0 = 0.f, sv0 = 0.f, s1 = 0.f, sv1 = 0.f;

    for (int p = 0; p < 2; ++p) {
        const int col = blk * CPB + p * 64 + (wave << 4) + (lane & 15);
        const float4* xp = reinterpret_cast<const float4*>(x)
                           + (size_t)b * C_IN * COLS + (size_t)c0 * COLS + col;

        float4 kh0 = make_float4(0.f, 0.f, 0.f, 0.f);
        float4 kh1 = kh0, vh0 = kh0, vh1 = kh0;

        #pragma unroll
        for (int i = 0; i < 16; ++i) {
            float4 xv = xp[(size_t)i * COLS];   // 4x 256B segments per wave-load
            float wk0 = s_w[0][c0 + i], wk1 = s_w[1][c0 + i];
            float wv0 = s_w[2][c0 + i], wv1 = s_w[3][c0 + i];
            kh0.x = fmaf(xv.x, wk0, kh0.x); kh0.y = fmaf(xv.y, wk0, kh0.y);
            kh0.z = fmaf(xv.z, wk0, kh0.z); kh0.w = fmaf(xv.w, wk0, kh0.w);
            kh1.x = fmaf(xv.x, wk1, kh1.x); kh1.y = fmaf(xv.y, wk1, kh1.y);
            kh1.z = fmaf(xv.z, wk1, kh1.z); kh1.w = fmaf(xv.w, wk1, kh1.w);
            vh0.x = fmaf(xv.x, wv0, vh0.x); vh0.y = fmaf(xv.y, wv0, vh0.y);
            vh0.z = fmaf(xv.z, wv0, vh0.z); vh0.w = fmaf(xv.w, wv0, vh0.w);
            vh1.x = fmaf(xv.x, wv1, vh1.x); vh1.y = fmaf(xv.y, wv1, vh1.y);
            vh1.z = fmaf(xv.z, wv1, vh1.z); vh1.w = fmaf(xv.w, wv1, vh1.w);
        }

        // Complete the dots across the 4 channel-chunks (lanes 16 apart share a
        // column); afterwards all 4 replicas hold identical full dots.
        #pragma unroll
        for (int off = 16; off <= 32; off <<= 1) {
            kh0.x += __shfl_xor(kh0.x, off); kh0.y += __shfl_xor(kh0.y, off);
            kh0.z += __shfl_xor(kh0.z, off); kh0.w += __shfl_xor(kh0.w, off);
            kh1.x += __shfl_xor(kh1.x, off); kh1.y += __shfl_xor(kh1.y, off);
            kh1.z += __shfl_xor(kh1.z, off); kh1.w += __shfl_xor(kh1.w, off);
            vh0.x += __shfl_xor(vh0.x, off); vh0.y += __shfl_xor(vh0.y, off);
            vh0.z += __shfl_xor(vh0.z, off); vh0.w += __shfl_xor(vh0.w, off);
            vh1.x += __shfl_xor(vh1.x, off); vh1.y += __shfl_xor(vh1.y, off);
            vh1.z += __shfl_xor(vh1.z, off); vh1.w += __shfl_xor(vh1.w, off);
        }

        float e;
        e = __expf(kh0.x); s0 += e; sv0 = fmaf(e, vh0.x, sv0);
        e = __expf(kh0.y); s0 += e; sv0 = fmaf(e, vh0.y, sv0);
        e = __expf(kh0.z); s0 += e; sv0 = fmaf(e, vh0.z, sv0);
        e = __expf(kh0.w); s0 += e; sv0 = fmaf(e, vh0.w, sv0);
        e = __expf(kh1.x); s1 += e; sv1 = fmaf(e, vh1.x, sv1);
        e = __expf(kh1.y); s1 += e; sv1 = fmaf(e, vh1.y, sv1);
        e = __expf(kh1.z); s1 += e; sv1 = fmaf(e, vh1.z, sv1);
        e = __expf(kh1.w); s1 += e; sv1 = fmaf(e, vh1.w, sv1);
    }

    // Sum the 16 distinct columns within each 16-lane group (replicas across
    // groups identical; off>=16 would double-count).
    #pragma unroll
    for (int off = 1; off <= 8; off <<= 1) {
        s0  += __shfl_xor(s0,  off);
        sv0 += __shfl_xor(sv0, off);
        s1  += __shfl_xor(s1,  off);
        sv1 += __shfl_xor(sv1, off);
    }
    if (lane == 0) s_red[wave] = make_float4(s0, sv0, s1, sv1);
    __syncthreads();
    if (tid == 0) {
        float4 r0 = s_red[0], r1 = s_red[1], r2 = s_red[2], r3 = s_red[3];
        partials[bid] = make_float4(r0.x + r1.x + r2.x + r3.x,
                                    r0.y + r1.y + r2.y + r3.y,
                                    r0.z + r1.z + r2.z + r3.z,
                                    r0.w + r1.w + r2.w + r3.w);
    }

    // ---------------- manual grid barrier (low-rate, relaxed polling) --------
    if (tid == 0) {
        __threadfence();                        // release partials (agent scope)
        __hip_atomic_fetch_add(cnt, 1u, __ATOMIC_RELAXED,
                               __HIP_MEMORY_SCOPE_AGENT);
        unsigned int v = __hip_atomic_load(cnt, __ATOMIC_RELAXED,
                                           __HIP_MEMORY_SCOPE_AGENT);
        while (v < GRID) {
            __builtin_amdgcn_s_sleep(127);      // ~8128 cyc ~= 3.4us per poll
            v = __hip_atomic_load(cnt, __ATOMIC_RELAXED,
                                  __HIP_MEMORY_SCOPE_AGENT);
        }
        (void)__hip_atomic_load(cnt, __ATOMIC_ACQUIRE,
                                __HIP_MEMORY_SCOPE_AGENT);
    }
    __syncthreads();

    // ---------------- Phase B: combine (fixed order) + fill ------------------
    // wave w owns (bb,h) = (w>>1, w&1); partials entry i = {s0,sv0,s1,sv1};
    // read (s,sv) pairs as agent-scope RELAXED atomic 8B loads (XCD-coherent).
    {
        const int bb = wave >> 1, h = wave & 1;
        const unsigned long long* pp =
            reinterpret_cast<const unsigned long long*>(partials);
        float s = 0.f, sv = 0.f;
        #pragma unroll
        for (int i = 0; i < BPB / 64; ++i) {    // 8 iterations
            unsigned long long raw = __hip_atomic_load(
                pp + ((size_t)(bb * BPB + i * 64 + lane) * 2 + h),
                __ATOMIC_RELAXED, __HIP_MEMORY_SCOPE_AGENT);
            float2 t;
            memcpy(&t, &raw, 8);
            s += t.x; sv += t.y;
        }
        #pragma unroll
        for (int off = 1; off <= 32; off <<= 1) {
            s  += __shfl_xor(s,  off);
            sv += __shfl_xor(sv, off);
        }
        if (lane == 0) s_ctx[bb][h] = sv / s;
    }
    __syncthreads();
    if (tid < 128) {
        const int bb = tid >> 6, o = tid & 63;
        s_vals[tid] = fmaf(Wout[o * 2 + 0], s_ctx[bb][0],
                      fmaf(Wout[o * 2 + 1], s_ctx[bb][1], bout[o]));
    }
    __syncthreads();

    // Fill this block's contiguous 128KB slice (8 blocks per output row).
    const int row = bid >> 3;                   // b*64 + o
    const float v = s_vals[row];
    const float4 f4 = make_float4(v, v, v, v);
    const size_t base = (size_t)bid * F4_PER_BLK;
    #pragma unroll 8
    for (int k = 0; k < F4_PER_BLK / BLK; ++k)
        out[base + ((size_t)k << 8) + tid] = f4;
}

extern "C" void kernel_launch(void* const* d_in, const int* in_sizes, int n_in,
                              void* d_out, int out_size, void* d_ws, size_t ws_size,
                              hipStream_t stream) {
    const float* x    = (const float*)d_in[0];
    // d_in[1] = query : dead (softmax over size-1 dim == 1)
    const float* Wqkv = (const float*)d_in[2];
    // d_in[3] = W_q   : dead
    const float* Wout = (const float*)d_in[4];
    const float* bout = (const float*)d_in[5];
    float4* out = (float4*)d_out;

    float4* partials = (float4*)d_ws;                          // 1024*16B = 16KB
    unsigned int* cnt = (unsigned int*)((char*)d_ws + 32768);  // barrier counter

    hipMemsetAsync(cnt, 0, sizeof(unsigned int), stream);      // graph-capturable
    fused_linattn<<<GRID, BLK, 0, stream>>>(x, Wqkv, Wout, bout, out,
                                            partials, cnt);
}

// Round 8
// 119.586 us; speedup vs baseline: 1.4846x; 1.3500x over previous
//
#include <hip/hip_runtime.h>
#include <math.h>
#include <string.h>

// LinearAttention3D, B=2, C=64, N = 128*128*16 = 262144, HEADS=2, DIM_HEAD=1.
// softmax over dim_head (size 1) == 1.0, SCALE == 1.0 -> q/query/W_q are dead.
// out[b,o,n] = W_out[o,:] . ctx[b,:] + b_out[o] (constant over n), where
// ctx[b,h] = (sum_n e^{k_h(n)} v_h(n)) / (sum_n e^{k_h(n)}).
// |k| <~ 5 so unstabilized fp32 exp-sums are safe -> combine is a plain add.
//
// R5/R6 lesson: in-kernel grid barrier is pathologically slow (~190us).
// Two-dispatch structure (R4, 50us) restored. New vs R4:
//  - combine runs ONCE, in k1's last block (atomic ticket), not per-k2-block;
//    partials re-read via relaxed agent-scope 8B atomic loads (proven R5/R6).
//  - k2 is a pure broadcast fill with NONTEMPORAL stores (via native
//    ext_vector_type — __builtin_nontemporal_store rejects HIP float4),
//    so `out` doesn't claim L3 and x can stay L3-resident across replays.

#define C_IN 64
#define COLS 65536                 // float4 columns per batch
#define BLK  256
#define NB1  1024                  // k1 blocks per batch (2048 total)
#define NBLK1 (2 * NB1)
#define CPB  64                    // float4-cols per k1 block
#define GRID2 1024
#define F4_PER_BLK 8192            // out float4 per k2 block (8388608 / 1024)

typedef float f32x4 __attribute__((ext_vector_type(4)));

// ---------------- Pass 1: projection + exp-sum reduce + last-block combine ----
// grid (NB1, 2), block 256 = 4 waves. Wave handles 16 cols x 4 channel-chunks;
// lane = chunk*16 + colidx; each thread loads 16 channels of one float4 column.
__global__ __launch_bounds__(BLK) void k1_proj_reduce(
    const float* __restrict__ x, const float* __restrict__ Wqkv,
    const float* __restrict__ Wout, const float* __restrict__ bout,
    float4* __restrict__ partials, float* __restrict__ vals,
    unsigned int* __restrict__ cnt)
{
    __shared__ float  s_w[4][C_IN];   // W_qkv rows 2..5: k_h0, k_h1, v_h0, v_h1
    __shared__ float4 s_red[4];
    __shared__ float  s_ctx[2][2];
    __shared__ unsigned int s_last;

    const int tid = threadIdx.x;
    const int b   = blockIdx.y;
    const int bid = b * NB1 + blockIdx.x;

    s_w[tid >> 6][tid & 63] = Wqkv[(2 + (tid >> 6)) * C_IN + (tid & 63)];
    __syncthreads();

    const int wave  = tid >> 6;
    const int lane  = tid & 63;
    const int chunk = lane >> 4;              // 0..3 -> channels [16*chunk, +16)
    const int c0    = chunk << 4;
    const int col   = blockIdx.x * CPB + (wave << 4) + (lane & 15);

    const float4* xp = reinterpret_cast<const float4*>(x)
                       + (size_t)b * C_IN * COLS + (size_t)c0 * COLS + col;

    float4 kh0 = make_float4(0.f, 0.f, 0.f, 0.f);
    float4 kh1 = kh0, vh0 = kh0, vh1 = kh0;

    #pragma unroll
    for (int i = 0; i < 16; ++i) {
        float4 xv = xp[(size_t)i * COLS];     // 4x 256B segments per wave-load
        float wk0 = s_w[0][c0 + i], wk1 = s_w[1][c0 + i];
        float wv0 = s_w[2][c0 + i], wv1 = s_w[3][c0 + i];
        kh0.x = fmaf(xv.x, wk0, kh0.x); kh0.y = fmaf(xv.y, wk0, kh0.y);
        kh0.z = fmaf(xv.z, wk0, kh0.z); kh0.w = fmaf(xv.w, wk0, kh0.w);
        kh1.x = fmaf(xv.x, wk1, kh1.x); kh1.y = fmaf(xv.y, wk1, kh1.y);
        kh1.z = fmaf(xv.z, wk1, kh1.z); kh1.w = fmaf(xv.w, wk1, kh1.w);
        vh0.x = fmaf(xv.x, wv0, vh0.x); vh0.y = fmaf(xv.y, wv0, vh0.y);
        vh0.z = fmaf(xv.z, wv0, vh0.z); vh0.w = fmaf(xv.w, wv0, vh0.w);
        vh1.x = fmaf(xv.x, wv1, vh1.x); vh1.y = fmaf(xv.y, wv1, vh1.y);
        vh1.z = fmaf(xv.z, wv1, vh1.z); vh1.w = fmaf(xv.w, wv1, vh1.w);
    }

    // Complete the dots across the 4 channel-chunks (lanes 16 apart share a
    // column); afterwards all 4 replicas hold identical full dots.
    #pragma unroll
    for (int off = 16; off <= 32; off <<= 1) {
        kh0.x += __shfl_xor(kh0.x, off); kh0.y += __shfl_xor(kh0.y, off);
        kh0.z += __shfl_xor(kh0.z, off); kh0.w += __shfl_xor(kh0.w, off);
        kh1.x += __shfl_xor(kh1.x, off); kh1.y += __shfl_xor(kh1.y, off);
        kh1.z += __shfl_xor(kh1.z, off); kh1.w += __shfl_xor(kh1.w, off);
        vh0.x += __shfl_xor(vh0.x, off); vh0.y += __shfl_xor(vh0.y, off);
        vh0.z += __shfl_xor(vh0.z, off); vh0.w += __shfl_xor(vh0.w, off);
        vh1.x += __shfl_xor(vh1.x, off); vh1.y += __shfl_xor(vh1.y, off);
        vh1.z += __shfl_xor(vh1.z, off); vh1.w += __shfl_xor(vh1.w, off);
    }

    // Unstabilized exp-sums (safe: |k| <~ 5).
    float s0 = 0.f, sv0 = 0.f, s1 = 0.f, sv1 = 0.f;
    float e;
    e = __expf(kh0.x); s0 += e; sv0 = fmaf(e, vh0.x, sv0);
    e = __expf(kh0.y); s0 += e; sv0 = fmaf(e, vh0.y, sv0);
    e = __expf(kh0.z); s0 += e; sv0 = fmaf(e, vh0.z, sv0);
    e = __expf(kh0.w); s0 += e; sv0 = fmaf(e, vh0.w, sv0);
    e = __expf(kh1.x); s1 += e; sv1 = fmaf(e, vh1.x, sv1);
    e = __expf(kh1.y); s1 += e; sv1 = fmaf(e, vh1.y, sv1);
    e = __expf(kh1.z); s1 += e; sv1 = fmaf(e, vh1.z, sv1);
    e = __expf(kh1.w); s1 += e; sv1 = fmaf(e, vh1.w, sv1);

    // Sum the 16 distinct columns within each 16-lane group (replicas across
    // groups identical; off>=16 would double-count).
    #pragma unroll
    for (int off = 1; off <= 8; off <<= 1) {
        s0  += __shfl_xor(s0,  off);
        sv0 += __shfl_xor(sv0, off);
        s1  += __shfl_xor(s1,  off);
        sv1 += __shfl_xor(sv1, off);
    }
    if (lane == 0) s_red[wave] = make_float4(s0, sv0, s1, sv1);
    __syncthreads();
    if (tid == 0) {
        float4 r0 = s_red[0], r1 = s_red[1], r2 = s_red[2], r3 = s_red[3];
        partials[bid] = make_float4(r0.x + r1.x + r2.x + r3.x,
                                    r0.y + r1.y + r2.y + r3.y,
                                    r0.z + r1.z + r2.z + r3.z,
                                    r0.w + r1.w + r2.w + r3.w);
        __threadfence();   // push partial to coherence point before ticket
        unsigned int old = __hip_atomic_fetch_add(
            cnt, 1u, __ATOMIC_RELAXED, __HIP_MEMORY_SCOPE_AGENT);
        s_last = (old == NBLK1 - 1) ? 1u : 0u;
    }
    __syncthreads();

    // ------ last block only: combine all partials (fixed order) -> vals -----
    if (s_last) {
        const int bb = wave >> 1, h = wave & 1;
        const unsigned long long* pp =
            reinterpret_cast<const unsigned long long*>(partials);
        float s = 0.f, sv = 0.f;
        #pragma unroll
        for (int i = 0; i < NB1 / 64; ++i) {    // 16 iterations
            unsigned long long raw = __hip_atomic_load(
                pp + ((size_t)(bb * NB1 + i * 64 + lane) * 2 + h),
                __ATOMIC_RELAXED, __HIP_MEMORY_SCOPE_AGENT);
            float2 t;
            memcpy(&t, &raw, 8);
            s += t.x; sv += t.y;
        }
        #pragma unroll
        for (int off = 1; off <= 32; off <<= 1) {
            s  += __shfl_xor(s,  off);
            sv += __shfl_xor(sv, off);
        }
        if (lane == 0) s_ctx[bb][h] = sv / s;
        __syncthreads();
        if (tid < 128) {
            const int b2 = tid >> 6, o = tid & 63;
            vals[tid] = fmaf(Wout[o * 2 + 0], s_ctx[b2][0],
                        fmaf(Wout[o * 2 + 1], s_ctx[b2][1], bout[o]));
        }
        // end-of-dispatch release makes vals visible to k2 (proven in R4)
    }
}

// ---------------- Pass 2: pure broadcast fill, nontemporal stores ------------
// grid GRID2, block 256; 8 blocks per output row; 128KB contiguous per block.
__global__ __launch_bounds__(BLK) void k2_fill(
    const float* __restrict__ vals, float* __restrict__ out)
{
    const int row = blockIdx.x >> 3;            // b*64 + o
    const float v = vals[row];                  // broadcast, L2-hot
    f32x4 f4 = { v, v, v, v };
    f32x4* o4 = reinterpret_cast<f32x4*>(out);
    const size_t base = (size_t)blockIdx.x * F4_PER_BLK;
    #pragma unroll 8
    for (int k = 0; k < F4_PER_BLK / BLK; ++k)
        __builtin_nontemporal_store(f4, &o4[base + ((size_t)k << 8) + threadIdx.x]);
}

extern "C" void kernel_launch(void* const* d_in, const int* in_sizes, int n_in,
                              void* d_out, int out_size, void* d_ws, size_t ws_size,
                              hipStream_t stream) {
    const float* x    = (const float*)d_in[0];
    // d_in[1] = query : dead (softmax over size-1 dim == 1)
    const float* Wqkv = (const float*)d_in[2];
    // d_in[3] = W_q   : dead
    const float* Wout = (const float*)d_in[4];
    const float* bout = (const float*)d_in[5];

    float4* partials  = (float4*)d_ws;                         // 2048*16B = 32KB
    float* vals       = (float*)((char*)d_ws + 65536);         // 128 floats
    unsigned int* cnt = (unsigned int*)((char*)d_ws + 131072); // ticket counter

    (void)hipMemsetAsync(cnt, 0, sizeof(unsigned int), stream); // graph-capturable
    k1_proj_reduce<<<dim3(NB1, 2), BLK, 0, stream>>>(x, Wqkv, Wout, bout,
                                                     partials, vals, cnt);
    k2_fill<<<GRID2, BLK, 0, stream>>>(vals, (float*)d_out);
}

// Round 9
// 53.304 us; speedup vs baseline: 3.3305x; 2.2435x over previous
//
#include <hip/hip_runtime.h>
#include <math.h>

// LinearAttention3D, B=2, C=64, N = 128*128*16 = 262144, HEADS=2, DIM_HEAD=1.
// softmax over dim_head (size 1) == 1.0, SCALE == 1.0 -> q/query/W_q are dead.
// out[b,o,n] = W_out[o,:] . ctx[b,:] + b_out[o] (constant over n), where
// ctx[b,h] = (sum_n e^{k_h(n)} v_h(n)) / (sum_n e^{k_h(n)}).
// |k| <~ 5 so unstabilized fp32 exp-sums are safe -> combine is a plain add.
//
// HARD LESSON (R5/R6/R8): agent-scope fences/atomics inside the hot kernels
// (grid barrier, last-block ticket) are catastrophic on MI355X — 3-5x
// slowdowns from cross-XCD L2 invalidate + serialized same-line RMWs.
// This is the proven R4 structure: two plain dispatches, visibility via the
// dispatch boundary, k2 redundantly combines the 32KB of partials per block
// (fixed order -> deterministic, L2-hot). One R8 keeper: NONTEMPORAL stores
// for `out`, which keep x L3-resident across graph replays (R8 counters:
// k1 replay FETCH ~ 0).

#define C_IN 64
#define COLS 65536                 // float4 columns per batch
#define BLK  256
#define NB1  1024                  // k1 blocks per batch (2048 total)
#define CPB  64                    // float4-cols per k1 block
#define GRID2 1024
#define F4_PER_BLK 8192            // out float4 per k2 block (8388608 / 1024)

typedef float f32x4 __attribute__((ext_vector_type(4)));

// ---------------- Pass 1: fused k/v projection + exp-sum partial reduction ---
// grid (NB1, 2), block 256 = 4 waves. Wave handles 16 cols x 4 channel-chunks;
// lane = chunk*16 + colidx; each thread loads 16 channels of one float4 column.
__global__ __launch_bounds__(BLK) void k1_proj_reduce(
    const float* __restrict__ x, const float* __restrict__ Wqkv,
    float4* __restrict__ partials /* [2][NB1] of {s0, sv0, s1, sv1} */)
{
    __shared__ float  s_w[4][C_IN];   // W_qkv rows 2..5: k_h0, k_h1, v_h0, v_h1
    __shared__ float4 s_red[4];
    const int tid = threadIdx.x;
    const int b = blockIdx.y;

    s_w[tid >> 6][tid & 63] = Wqkv[(2 + (tid >> 6)) * C_IN + (tid & 63)];
    __syncthreads();

    const int wave  = tid >> 6;
    const int lane  = tid & 63;
    const int chunk = lane >> 4;              // 0..3 -> channels [16*chunk, +16)
    const int c0    = chunk << 4;
    const int col   = blockIdx.x * CPB + (wave << 4) + (lane & 15);

    const float4* xp = reinterpret_cast<const float4*>(x)
                       + (size_t)b * C_IN * COLS + (size_t)c0 * COLS + col;

    float4 kh0 = make_float4(0.f, 0.f, 0.f, 0.f);
    float4 kh1 = kh0, vh0 = kh0, vh1 = kh0;

    #pragma unroll
    for (int i = 0; i < 16; ++i) {
        float4 xv = xp[(size_t)i * COLS];     // 4x 256B segments per wave-load
        float wk0 = s_w[0][c0 + i], wk1 = s_w[1][c0 + i];
        float wv0 = s_w[2][c0 + i], wv1 = s_w[3][c0 + i];
        kh0.x = fmaf(xv.x, wk0, kh0.x); kh0.y = fmaf(xv.y, wk0, kh0.y);
        kh0.z = fmaf(xv.z, wk0, kh0.z); kh0.w = fmaf(xv.w, wk0, kh0.w);
        kh1.x = fmaf(xv.x, wk1, kh1.x); kh1.y = fmaf(xv.y, wk1, kh1.y);
        kh1.z = fmaf(xv.z, wk1, kh1.z); kh1.w = fmaf(xv.w, wk1, kh1.w);
        vh0.x = fmaf(xv.x, wv0, vh0.x); vh0.y = fmaf(xv.y, wv0, vh0.y);
        vh0.z = fmaf(xv.z, wv0, vh0.z); vh0.w = fmaf(xv.w, wv0, vh0.w);
        vh1.x = fmaf(xv.x, wv1, vh1.x); vh1.y = fmaf(xv.y, wv1, vh1.y);
        vh1.z = fmaf(xv.z, wv1, vh1.z); vh1.w = fmaf(xv.w, wv1, vh1.w);
    }

    // Complete the dots across the 4 channel-chunks (lanes 16 apart share a
    // column); afterwards all 4 replicas hold identical full dots.
    #pragma unroll
    for (int off = 16; off <= 32; off <<= 1) {
        kh0.x += __shfl_xor(kh0.x, off); kh0.y += __shfl_xor(kh0.y, off);
        kh0.z += __shfl_xor(kh0.z, off); kh0.w += __shfl_xor(kh0.w, off);
        kh1.x += __shfl_xor(kh1.x, off); kh1.y += __shfl_xor(kh1.y, off);
        kh1.z += __shfl_xor(kh1.z, off); kh1.w += __shfl_xor(kh1.w, off);
        vh0.x += __shfl_xor(vh0.x, off); vh0.y += __shfl_xor(vh0.y, off);
        vh0.z += __shfl_xor(vh0.z, off); vh0.w += __shfl_xor(vh0.w, off);
        vh1.x += __shfl_xor(vh1.x, off); vh1.y += __shfl_xor(vh1.y, off);
        vh1.z += __shfl_xor(vh1.z, off); vh1.w += __shfl_xor(vh1.w, off);
    }

    // Unstabilized exp-sums (safe: |k| <~ 5).
    float s0 = 0.f, sv0 = 0.f, s1 = 0.f, sv1 = 0.f;
    float e;
    e = __expf(kh0.x); s0 += e; sv0 = fmaf(e, vh0.x, sv0);
    e = __expf(kh0.y); s0 += e; sv0 = fmaf(e, vh0.y, sv0);
    e = __expf(kh0.z); s0 += e; sv0 = fmaf(e, vh0.z, sv0);
    e = __expf(kh0.w); s0 += e; sv0 = fmaf(e, vh0.w, sv0);
    e = __expf(kh1.x); s1 += e; sv1 = fmaf(e, vh1.x, sv1);
    e = __expf(kh1.y); s1 += e; sv1 = fmaf(e, vh1.y, sv1);
    e = __expf(kh1.z); s1 += e; sv1 = fmaf(e, vh1.z, sv1);
    e = __expf(kh1.w); s1 += e; sv1 = fmaf(e, vh1.w, sv1);

    // Sum the 16 distinct columns within each 16-lane group (replicas across
    // groups identical; off>=16 would double-count).
    #pragma unroll
    for (int off = 1; off <= 8; off <<= 1) {
        s0  += __shfl_xor(s0,  off);
        sv0 += __shfl_xor(sv0, off);
        s1  += __shfl_xor(s1,  off);
        sv1 += __shfl_xor(sv1, off);
    }
    if (lane == 0) s_red[wave] = make_float4(s0, sv0, s1, sv1);
    __syncthreads();
    if (tid == 0) {
        float4 r0 = s_red[0], r1 = s_red[1], r2 = s_red[2], r3 = s_red[3];
        partials[(size_t)b * NB1 + blockIdx.x] =
            make_float4(r0.x + r1.x + r2.x + r3.x,
                        r0.y + r1.y + r2.y + r3.y,
                        r0.z + r1.z + r2.z + r3.z,
                        r0.w + r1.w + r2.w + r3.w);
    }
}

// ---------------- Pass 2: redundant per-block combine + nontemporal fill -----
// grid GRID2, block 256. Every block combines all partials in a FIXED order
// (deterministic, 32KB L2-hot), then fills its contiguous 128KB slice of out
// with nontemporal stores (out never claims L3 -> x stays L3-resident).
__global__ __launch_bounds__(BLK) void k2_combine_fill(
    const float* __restrict__ partials,
    const float* __restrict__ Wout,
    const float* __restrict__ bout,
    float* __restrict__ out)
{
    __shared__ float s_ctx[2][2];
    const int tid = threadIdx.x;
    const int wave = tid >> 6, lane = tid & 63;
    const int b = wave >> 1, h = wave & 1;

    // wave (b,h): sum 1024 partial (s, sv) pairs, lane-strided + butterfly.
    const float2* p2 = reinterpret_cast<const float2*>(partials);
    float s = 0.f, sv = 0.f;
    #pragma unroll
    for (int i = 0; i < NB1 / 64; ++i) {
        float2 t = p2[(size_t)(b * NB1 + i * 64 + lane) * 2 + h];
        s += t.x; sv += t.y;
    }
    #pragma unroll
    for (int off = 1; off <= 32; off <<= 1) {
        s  += __shfl_xor(s,  off);
        sv += __shfl_xor(sv, off);
    }
    if (lane == 0) s_ctx[b][h] = sv / s;
    __syncthreads();

    // This block's slice lies inside a single output row (8 blocks per row).
    const int row = blockIdx.x >> 3;            // b*64 + o
    const int bb = row >> 6, o = row & 63;
    const float v = fmaf(Wout[o * 2 + 0], s_ctx[bb][0],
                    fmaf(Wout[o * 2 + 1], s_ctx[bb][1], bout[o]));
    const f32x4 f4 = { v, v, v, v };

    f32x4* o4 = reinterpret_cast<f32x4*>(out);
    const size_t base = (size_t)blockIdx.x * F4_PER_BLK;
    #pragma unroll 8
    for (int k = 0; k < F4_PER_BLK / BLK; ++k)
        __builtin_nontemporal_store(f4, &o4[base + ((size_t)k << 8) + tid]);
}

extern "C" void kernel_launch(void* const* d_in, const int* in_sizes, int n_in,
                              void* d_out, int out_size, void* d_ws, size_t ws_size,
                              hipStream_t stream) {
    const float* x    = (const float*)d_in[0];
    // d_in[1] = query : dead (softmax over size-1 dim == 1)
    const float* Wqkv = (const float*)d_in[2];
    // d_in[3] = W_q   : dead
    const float* Wout = (const float*)d_in[4];
    const float* bout = (const float*)d_in[5];

    float4* partials = (float4*)d_ws;           // 2*1024 float4 = 32 KB

    k1_proj_reduce<<<dim3(NB1, 2), BLK, 0, stream>>>(x, Wqkv, partials);
    k2_combine_fill<<<GRID2, BLK, 0, stream>>>((const float*)partials, Wout,
                                               bout, (float*)d_out);
}

// Round 10
// 51.754 us; speedup vs baseline: 3.4303x; 1.0300x over previous
//
#include <hip/hip_runtime.h>
#include <math.h>

// LinearAttention3D, B=2, C=64, N = 128*128*16 = 262144, HEADS=2, DIM_HEAD=1.
// softmax over dim_head (size 1) == 1.0, SCALE == 1.0 -> q/query/W_q are dead.
// out[b,o,n] = W_out[o,:] . ctx[b,:] + b_out[o] (constant over n), where
// ctx[b,h] = (sum_n e^{k_h(n)} v_h(n)) / (sum_n e^{k_h(n)}).
// |k| <~ 5 so unstabilized fp32 exp-sums are safe -> combine is a plain add.
//
// Lessons so far: agent-scope fences/atomics in hot kernels are catastrophic
// (R5/R6/R8); nontemporal stores on `out` regress (R9: +3.3us). This round:
// R4's proven two-phase structure, PIPELINED BY BATCH. ctx[b] depends only on
// x[b], so b=1's reads can overlap b=0's writes in a single mixed dispatch
// (block-uniform role branch, no cross-block sync, all sync via dispatch
// boundaries).

#define C_IN 64
#define COLS 65536                 // float4 columns per batch
#define BLK  256
#define NB1  1024                  // proj blocks per batch
#define CPB  64                    // float4-cols per proj block
#define FILLB 512                  // fill blocks per batch
#define F4_PER_FILL 8192           // out float4 per fill block (4194304/512)

typedef float f32x4 __attribute__((ext_vector_type(4)));

// ---- proj+reduce body (R4-proven): 4 waves, 16 cols x 4 channel-chunks ------
__device__ __forceinline__ void proj_reduce_body(
    const float* __restrict__ x, const float* __restrict__ Wqkv,
    float4* __restrict__ partials, const int b, const int blk,
    float (*s_w)[C_IN], float4* s_red)
{
    const int tid = threadIdx.x;
    s_w[tid >> 6][tid & 63] = Wqkv[(2 + (tid >> 6)) * C_IN + (tid & 63)];
    __syncthreads();

    const int wave  = tid >> 6;
    const int lane  = tid & 63;
    const int chunk = lane >> 4;              // 0..3 -> channels [16*chunk, +16)
    const int c0    = chunk << 4;
    const int col   = blk * CPB + (wave << 4) + (lane & 15);

    const float4* xp = reinterpret_cast<const float4*>(x)
                       + (size_t)b * C_IN * COLS + (size_t)c0 * COLS + col;

    float4 kh0 = make_float4(0.f, 0.f, 0.f, 0.f);
    float4 kh1 = kh0, vh0 = kh0, vh1 = kh0;

    #pragma unroll
    for (int i = 0; i < 16; ++i) {
        float4 xv = xp[(size_t)i * COLS];     // 4x 256B segments per wave-load
        float wk0 = s_w[0][c0 + i], wk1 = s_w[1][c0 + i];
        float wv0 = s_w[2][c0 + i], wv1 = s_w[3][c0 + i];
        kh0.x = fmaf(xv.x, wk0, kh0.x); kh0.y = fmaf(xv.y, wk0, kh0.y);
        kh0.z = fmaf(xv.z, wk0, kh0.z); kh0.w = fmaf(xv.w, wk0, kh0.w);
        kh1.x = fmaf(xv.x, wk1, kh1.x); kh1.y = fmaf(xv.y, wk1, kh1.y);
        kh1.z = fmaf(xv.z, wk1, kh1.z); kh1.w = fmaf(xv.w, wk1, kh1.w);
        vh0.x = fmaf(xv.x, wv0, vh0.x); vh0.y = fmaf(xv.y, wv0, vh0.y);
        vh0.z = fmaf(xv.z, wv0, vh0.z); vh0.w = fmaf(xv.w, wv0, vh0.w);
        vh1.x = fmaf(xv.x, wv1, vh1.x); vh1.y = fmaf(xv.y, wv1, vh1.y);
        vh1.z = fmaf(xv.z, wv1, vh1.z); vh1.w = fmaf(xv.w, wv1, vh1.w);
    }

    // Complete the dots across the 4 channel-chunks (lanes 16 apart share a
    // column); afterwards all 4 replicas hold identical full dots.
    #pragma unroll
    for (int off = 16; off <= 32; off <<= 1) {
        kh0.x += __shfl_xor(kh0.x, off); kh0.y += __shfl_xor(kh0.y, off);
        kh0.z += __shfl_xor(kh0.z, off); kh0.w += __shfl_xor(kh0.w, off);
        kh1.x += __shfl_xor(kh1.x, off); kh1.y += __shfl_xor(kh1.y, off);
        kh1.z += __shfl_xor(kh1.z, off); kh1.w += __shfl_xor(kh1.w, off);
        vh0.x += __shfl_xor(vh0.x, off); vh0.y += __shfl_xor(vh0.y, off);
        vh0.z += __shfl_xor(vh0.z, off); vh0.w += __shfl_xor(vh0.w, off);
        vh1.x += __shfl_xor(vh1.x, off); vh1.y += __shfl_xor(vh1.y, off);
        vh1.z += __shfl_xor(vh1.z, off); vh1.w += __shfl_xor(vh1.w, off);
    }

    // Unstabilized exp-sums (safe: |k| <~ 5).
    float s0 = 0.f, sv0 = 0.f, s1 = 0.f, sv1 = 0.f;
    float e;
    e = __expf(kh0.x); s0 += e; sv0 = fmaf(e, vh0.x, sv0);
    e = __expf(kh0.y); s0 += e; sv0 = fmaf(e, vh0.y, sv0);
    e = __expf(kh0.z); s0 += e; sv0 = fmaf(e, vh0.z, sv0);
    e = __expf(kh0.w); s0 += e; sv0 = fmaf(e, vh0.w, sv0);
    e = __expf(kh1.x); s1 += e; sv1 = fmaf(e, vh1.x, sv1);
    e = __expf(kh1.y); s1 += e; sv1 = fmaf(e, vh1.y, sv1);
    e = __expf(kh1.z); s1 += e; sv1 = fmaf(e, vh1.z, sv1);
    e = __expf(kh1.w); s1 += e; sv1 = fmaf(e, vh1.w, sv1);

    // Sum the 16 distinct columns within each 16-lane group (replicas across
    // groups identical; off>=16 would double-count).
    #pragma unroll
    for (int off = 1; off <= 8; off <<= 1) {
        s0  += __shfl_xor(s0,  off);
        sv0 += __shfl_xor(sv0, off);
        s1  += __shfl_xor(s1,  off);
        sv1 += __shfl_xor(sv1, off);
    }
    if (lane == 0) s_red[wave] = make_float4(s0, sv0, s1, sv1);
    __syncthreads();
    if (tid == 0) {
        float4 r0 = s_red[0], r1 = s_red[1], r2 = s_red[2], r3 = s_red[3];
        partials[(size_t)b * NB1 + blk] =
            make_float4(r0.x + r1.x + r2.x + r3.x,
                        r0.y + r1.y + r2.y + r3.y,
                        r0.z + r1.z + r2.z + r3.z,
                        r0.w + r1.w + r2.w + r3.w);
    }
}

// ---- combine+fill body (R4-proven combine; plain stores) --------------------
// Redundant per-block combine of batch bb's 1024 partials in FIXED order
// (deterministic, 16KB L2-hot), then fill a contiguous 128KB slice of out.
__device__ __forceinline__ void combine_fill_body(
    const float* __restrict__ partials, const float* __restrict__ Wout,
    const float* __restrict__ bout, float* __restrict__ out,
    const int bb, const int fblk, float* s_ctx /* [2] */)
{
    const int tid = threadIdx.x;
    const int wave = tid >> 6, lane = tid & 63;

    if (wave < 2) {                 // wave h sums batch bb's (s,sv) for head h
        const int h = wave;
        const float2* p2 = reinterpret_cast<const float2*>(partials);
        float s = 0.f, sv = 0.f;
        #pragma unroll
        for (int i = 0; i < NB1 / 64; ++i) {
            float2 t = p2[(size_t)((bb * NB1 + i * 64 + lane) * 2 + h)];
            s += t.x; sv += t.y;
        }
        #pragma unroll
        for (int off = 1; off <= 32; off <<= 1) {
            s  += __shfl_xor(s,  off);
            sv += __shfl_xor(sv, off);
        }
        if (lane == 0) s_ctx[h] = sv / s;
    }
    __syncthreads();

    const int row = bb * 64 + (fblk >> 3);      // 8 fill blocks per output row
    const int o = row & 63;
    const float v = fmaf(Wout[o * 2 + 0], s_ctx[0],
                    fmaf(Wout[o * 2 + 1], s_ctx[1], bout[o]));
    const f32x4 f4 = { v, v, v, v };

    f32x4* o4 = reinterpret_cast<f32x4*>(out);
    const size_t base = (size_t)row * COLS + (size_t)(fblk & 7) * F4_PER_FILL;
    #pragma unroll 8
    for (int k = 0; k < F4_PER_FILL / BLK; ++k)
        o4[base + ((size_t)k << 8) + tid] = f4;
}

// ---- D1: proj-reduce batch 0 ------------------------------------------------
__global__ __launch_bounds__(BLK) void k_proj0(
    const float* __restrict__ x, const float* __restrict__ Wqkv,
    float4* __restrict__ partials)
{
    __shared__ float  s_w[4][C_IN];
    __shared__ float4 s_red[4];
    proj_reduce_body(x, Wqkv, partials, 0, blockIdx.x, s_w, s_red);
}

// ---- D2: proj-reduce batch 1 (blocks 0..1023)  ||  fill batch 0 (1024..1535) -
__global__ __launch_bounds__(BLK) void k_mix(
    const float* __restrict__ x, const float* __restrict__ Wqkv,
    float4* __restrict__ partials, const float* __restrict__ Wout,
    const float* __restrict__ bout, float* __restrict__ out)
{
    __shared__ float  s_w[4][C_IN];
    __shared__ float4 s_red[4];
    __shared__ float  s_ctx[2];
    if (blockIdx.x < NB1) {
        proj_reduce_body(x, Wqkv, partials, 1, blockIdx.x, s_w, s_red);
    } else {
        combine_fill_body((const float*)partials, Wout, bout, out,
                          0, blockIdx.x - NB1, s_ctx);
    }
}

// ---- D3: fill batch 1 --------------------------------------------------------
__global__ __launch_bounds__(BLK) void k_fill1(
    const float* __restrict__ partials, const float* __restrict__ Wout,
    const float* __restrict__ bout, float* __restrict__ out)
{
    __shared__ float s_ctx[2];
    combine_fill_body(partials, Wout, bout, out, 1, blockIdx.x, s_ctx);
}

extern "C" void kernel_launch(void* const* d_in, const int* in_sizes, int n_in,
                              void* d_out, int out_size, void* d_ws, size_t ws_size,
                              hipStream_t stream) {
    const float* x    = (const float*)d_in[0];
    // d_in[1] = query : dead (softmax over size-1 dim == 1)
    const float* Wqkv = (const float*)d_in[2];
    // d_in[3] = W_q   : dead
    const float* Wout = (const float*)d_in[4];
    const float* bout = (const float*)d_in[5];
    float* out = (float*)d_out;

    float4* partials = (float4*)d_ws;           // 2*1024 float4 = 32 KB

    k_proj0<<<NB1, BLK, 0, stream>>>(x, Wqkv, partials);
    k_mix<<<NB1 + FILLB, BLK, 0, stream>>>(x, Wqkv, partials, Wout, bout, out);
    k_fill1<<<FILLB, BLK, 0, stream>>>((const float*)partials, Wout, bout, out);
}

// Round 11
// 49.295 us; speedup vs baseline: 3.6014x; 1.0499x over previous
//
#include <hip/hip_runtime.h>
#include <math.h>

// LinearAttention3D, B=2, C=64, N = 128*128*16 = 262144, HEADS=2, DIM_HEAD=1.
// softmax over dim_head (size 1) == 1.0, SCALE == 1.0 -> q/query/W_q are dead.
// out[b,o,n] = W_out[o,:] . ctx[b,:] + b_out[o] (constant over n), where
// ctx[b,h] = (sum_n e^{k_h(n)} v_h(n)) / (sum_n e^{k_h(n)}).
// |k| <~ 5 so unstabilized fp32 exp-sums are safe -> combine is a plain add.
//
// Lessons: agent-scope fences/atomics in hot kernels catastrophic (R5/R6/R8);
// nt-stores regress (R9); batch-pipeline neutral (R10). R4 2-dispatch base.
// THIS round: k1 read pattern 4x256B-segments/wave -> 1KB-contiguous/wave
// (the pattern harness fills hit 88-90% of peak with). Each lane owns one
// float4 column; waves split channels 4-way interleaved; cross-wave combine
// via conflict-free LDS tile; exp + butterfly in wave 0. Fixed order.

#define C_IN 64
#define COLS 65536                 // float4 columns per batch
#define BLK  256
#define NB1  1024                  // k1 blocks per batch (2048 total)
#define CPB  64                    // float4-cols per k1 block (= 1KB wide)
#define GRID2 1024
#define F4_PER_BLK 8192            // out float4 per k2 block (8388608 / 1024)

typedef float f32x4 __attribute__((ext_vector_type(4)));

// ---------------- Pass 1: fused k/v projection + exp-sum partial reduction ---
// grid (NB1, 2), block 256 = 4 waves. Block tile: 64 channels x 64 float4-cols.
// Wave w, iter i reads channel c=4i+w as ONE 1KB-contiguous wave-load
// (lane l -> column col0+l). Cross-wave channel-partials combined in LDS.
__global__ __launch_bounds__(BLK) void k1_proj_reduce(
    const float* __restrict__ x, const float* __restrict__ Wqkv,
    float4* __restrict__ partials /* [2][NB1] of {s0, sv0, s1, sv1} */)
{
    __shared__ float  s_w[4][C_IN];      // W_qkv rows 2..5: k0, k1, v0, v1
    __shared__ float4 s_part[4][4][64];  // [quantity][wave][lane] - 16KB
    const int tid = threadIdx.x;
    const int b = blockIdx.y;

    s_w[tid >> 6][tid & 63] = Wqkv[(2 + (tid >> 6)) * C_IN + (tid & 63)];
    __syncthreads();

    const int wave = tid >> 6;
    const int lane = tid & 63;
    const int col  = blockIdx.x * CPB + lane;   // this lane's float4 column

    const float4* xp = reinterpret_cast<const float4*>(x)
                       + (size_t)b * C_IN * COLS + (size_t)wave * COLS + col;

    float4 kh0 = make_float4(0.f, 0.f, 0.f, 0.f);
    float4 kh1 = kh0, vh0 = kh0, vh1 = kh0;

    #pragma unroll
    for (int i = 0; i < 16; ++i) {
        const int c = (i << 2) + wave;          // channel 4i+w
        float4 xv = xp[(size_t)(i << 2) * COLS]; // 1KB contiguous per wave-load
        float wk0 = s_w[0][c], wk1 = s_w[1][c];
        float wv0 = s_w[2][c], wv1 = s_w[3][c];
        kh0.x = fmaf(xv.x, wk0, kh0.x); kh0.y = fmaf(xv.y, wk0, kh0.y);
        kh0.z = fmaf(xv.z, wk0, kh0.z); kh0.w = fmaf(xv.w, wk0, kh0.w);
        kh1.x = fmaf(xv.x, wk1, kh1.x); kh1.y = fmaf(xv.y, wk1, kh1.y);
        kh1.z = fmaf(xv.z, wk1, kh1.z); kh1.w = fmaf(xv.w, wk1, kh1.w);
        vh0.x = fmaf(xv.x, wv0, vh0.x); vh0.y = fmaf(xv.y, wv0, vh0.y);
        vh0.z = fmaf(xv.z, wv0, vh0.z); vh0.w = fmaf(xv.w, wv0, vh0.w);
        vh1.x = fmaf(xv.x, wv1, vh1.x); vh1.y = fmaf(xv.y, wv1, vh1.y);
        vh1.z = fmaf(xv.z, wv1, vh1.z); vh1.w = fmaf(xv.w, wv1, vh1.w);
    }

    // Per-wave channel-partials -> LDS. For fixed [q][w], lanes write 16B
    // consecutive -> conflict-free.
    s_part[0][wave][lane] = kh0;
    s_part[1][wave][lane] = kh1;
    s_part[2][wave][lane] = vh0;
    s_part[3][wave][lane] = vh1;
    __syncthreads();

    // Wave 0: combine 4 wave-partials per column (full dots), exp, reduce.
    if (tid < 64) {
        float4 p0, p1, p2, p3;

        p0 = s_part[0][0][tid]; p1 = s_part[0][1][tid];
        p2 = s_part[0][2][tid]; p3 = s_part[0][3][tid];
        float4 K0 = make_float4(p0.x + p1.x + p2.x + p3.x,
                                p0.y + p1.y + p2.y + p3.y,
                                p0.z + p1.z + p2.z + p3.z,
                                p0.w + p1.w + p2.w + p3.w);
        p0 = s_part[1][0][tid]; p1 = s_part[1][1][tid];
        p2 = s_part[1][2][tid]; p3 = s_part[1][3][tid];
        float4 K1 = make_float4(p0.x + p1.x + p2.x + p3.x,
                                p0.y + p1.y + p2.y + p3.y,
                                p0.z + p1.z + p2.z + p3.z,
                                p0.w + p1.w + p2.w + p3.w);
        p0 = s_part[2][0][tid]; p1 = s_part[2][1][tid];
        p2 = s_part[2][2][tid]; p3 = s_part[2][3][tid];
        float4 V0 = make_float4(p0.x + p1.x + p2.x + p3.x,
                                p0.y + p1.y + p2.y + p3.y,
                                p0.z + p1.z + p2.z + p3.z,
                                p0.w + p1.w + p2.w + p3.w);
        p0 = s_part[3][0][tid]; p1 = s_part[3][1][tid];
        p2 = s_part[3][2][tid]; p3 = s_part[3][3][tid];
        float4 V1 = make_float4(p0.x + p1.x + p2.x + p3.x,
                                p0.y + p1.y + p2.y + p3.y,
                                p0.z + p1.z + p2.z + p3.z,
                                p0.w + p1.w + p2.w + p3.w);

        // Unstabilized exp-sums (safe: |k| <~ 5).
        float s0 = 0.f, sv0 = 0.f, s1 = 0.f, sv1 = 0.f;
        float e;
        e = __expf(K0.x); s0 += e; sv0 = fmaf(e, V0.x, sv0);
        e = __expf(K0.y); s0 += e; sv0 = fmaf(e, V0.y, sv0);
        e = __expf(K0.z); s0 += e; sv0 = fmaf(e, V0.z, sv0);
        e = __expf(K0.w); s0 += e; sv0 = fmaf(e, V0.w, sv0);
        e = __expf(K1.x); s1 += e; sv1 = fmaf(e, V1.x, sv1);
        e = __expf(K1.y); s1 += e; sv1 = fmaf(e, V1.y, sv1);
        e = __expf(K1.z); s1 += e; sv1 = fmaf(e, V1.z, sv1);
        e = __expf(K1.w); s1 += e; sv1 = fmaf(e, V1.w, sv1);

        // Butterfly over the 64 columns.
        #pragma unroll
        for (int off = 1; off <= 32; off <<= 1) {
            s0  += __shfl_xor(s0,  off);
            sv0 += __shfl_xor(sv0, off);
            s1  += __shfl_xor(s1,  off);
            sv1 += __shfl_xor(sv1, off);
        }
        if (tid == 0)
            partials[(size_t)b * NB1 + blockIdx.x] =
                make_float4(s0, sv0, s1, sv1);
    }
}

// ---------------- Pass 2: redundant per-block combine + plain fill -----------
// grid GRID2, block 256. Every block combines all partials in a FIXED order
// (deterministic, 32KB L2-hot), then fills its contiguous 128KB slice of out.
__global__ __launch_bounds__(BLK) void k2_combine_fill(
    const float* __restrict__ partials,
    const float* __restrict__ Wout,
    const float* __restrict__ bout,
    float* __restrict__ out)
{
    __shared__ float s_ctx[2][2];
    const int tid = threadIdx.x;
    const int wave = tid >> 6, lane = tid & 63;
    const int b = wave >> 1, h = wave & 1;

    // wave (b,h): sum 1024 partial (s, sv) pairs, lane-strided + butterfly.
    const float2* p2 = reinterpret_cast<const float2*>(partials);
    float s = 0.f, sv = 0.f;
    #pragma unroll
    for (int i = 0; i < NB1 / 64; ++i) {
        float2 t = p2[(size_t)(b * NB1 + i * 64 + lane) * 2 + h];
        s += t.x; sv += t.y;
    }
    #pragma unroll
    for (int off = 1; off <= 32; off <<= 1) {
        s  += __shfl_xor(s,  off);
        sv += __shfl_xor(sv, off);
    }
    if (lane == 0) s_ctx[b][h] = sv / s;
    __syncthreads();

    // This block's slice lies inside a single output row (8 blocks per row).
    const int row = blockIdx.x >> 3;            // b*64 + o
    const int bb = row >> 6, o = row & 63;
    const float v = fmaf(Wout[o * 2 + 0], s_ctx[bb][0],
                    fmaf(Wout[o * 2 + 1], s_ctx[bb][1], bout[o]));
    const float4 f4 = make_float4(v, v, v, v);

    float4* o4 = reinterpret_cast<float4*>(out);
    const size_t base = (size_t)blockIdx.x * F4_PER_BLK;
    #pragma unroll 8
    for (int k = 0; k < F4_PER_BLK / BLK; ++k)
        o4[base + ((size_t)k << 8) + tid] = f4;
}

extern "C" void kernel_launch(void* const* d_in, const int* in_sizes, int n_in,
                              void* d_out, int out_size, void* d_ws, size_t ws_size,
                              hipStream_t stream) {
    const float* x    = (const float*)d_in[0];
    // d_in[1] = query : dead (softmax over size-1 dim == 1)
    const float* Wqkv = (const float*)d_in[2];
    // d_in[3] = W_q   : dead
    const float* Wout = (const float*)d_in[4];
    const float* bout = (const float*)d_in[5];

    float4* partials = (float4*)d_ws;           // 2*1024 float4 = 32 KB

    k1_proj_reduce<<<dim3(NB1, 2), BLK, 0, stream>>>(x, Wqkv, partials);
    k2_combine_fill<<<GRID2, BLK, 0, stream>>>((const float*)partials, Wout,
                                               bout, (float*)d_out);
}